// Round 3
// baseline (843.919 us; speedup 1.0000x reference)
//
#include <hip/hip_runtime.h>

#define N_NODES 100000
#define N_EDGES 1600000
#define D 64
#define NPB 128                                   // nodes per bucket (dst >> 7)
#define NBUCK ((N_NODES + NPB - 1) / NPB)         // 782
#define CHUNK 8192                                // edges per partition block
#define NCHUNK ((N_EDGES + CHUNK - 1) / CHUNK)    // 196

// ---------------------------------------------------------------- zero bucket totals
__global__ __launch_bounds__(1024) void zero_totals(int* __restrict__ p) {
    int t = threadIdx.x;
    if (t < NBUCK) p[t] = 0;
}

// ---------------------------------------------------------------- bucket histogram (LDS-staged)
__global__ __launch_bounds__(256) void hist_kernel(const int* __restrict__ col,
                                                   int* __restrict__ bucketTotals) {
    __shared__ int h[NBUCK];
    for (int k = threadIdx.x; k < NBUCK; k += 256) h[k] = 0;
    __syncthreads();
    int base = blockIdx.x * CHUNK;
    #pragma unroll
    for (int it = 0; it < CHUNK / 256; ++it) {
        int e = base + it * 256 + threadIdx.x;
        if (e < N_EDGES) atomicAdd(&h[col[e] >> 7], 1);
    }
    __syncthreads();
    for (int k = threadIdx.x; k < NBUCK; k += 256)
        if (h[k]) atomicAdd(&bucketTotals[k], h[k]);
}

// ---------------------------------------------------------------- exclusive scan of 782 totals (1 block)
__global__ __launch_bounds__(1024) void scan_kernel(const int* __restrict__ totals,
                                                    int* __restrict__ base_,
                                                    int* __restrict__ cursor) {
    int tid = threadIdx.x;
    int v = (tid < NBUCK) ? totals[tid] : 0;
    int lane = tid & 63, wave = tid >> 6;
    int s = v;
    #pragma unroll
    for (int o = 1; o < 64; o <<= 1) {
        int t = __shfl_up(s, o, 64);
        if (lane >= o) s += t;
    }
    __shared__ int ws[16];
    if (lane == 63) ws[wave] = s;
    __syncthreads();
    if (wave == 0 && lane < 16) {
        int w = ws[lane];
        #pragma unroll
        for (int o = 1; o < 16; o <<= 1) {
            int t = __shfl_up(w, o, 64);
            if (lane >= o) w += t;
        }
        ws[lane] = w;
    }
    __syncthreads();
    int excl = s - v + (wave ? ws[wave - 1] : 0);
    if (tid < NBUCK) { base_[tid] = excl; cursor[tid] = excl; }
}

// ---------------------------------------------------------------- partition: bucketed edge runs
// Each block reserves one contiguous run per bucket, so scattered writes stay
// within block-owned regions (no cross-XCD partial-line sharing except at run edges).
__global__ __launch_bounds__(256) void partition_kernel(const int* __restrict__ row,
                                                        const int* __restrict__ col,
                                                        int* __restrict__ cursor,
                                                        int* __restrict__ edges) {
    __shared__ int cnt[NBUCK];
    __shared__ int runStart[NBUCK];
    __shared__ int rank[NBUCK];
    for (int k = threadIdx.x; k < NBUCK; k += 256) { cnt[k] = 0; rank[k] = 0; }
    __syncthreads();
    int base = blockIdx.x * CHUNK;
    #pragma unroll
    for (int it = 0; it < CHUNK / 256; ++it) {
        int e = base + it * 256 + threadIdx.x;
        if (e < N_EDGES) atomicAdd(&cnt[col[e] >> 7], 1);
    }
    __syncthreads();
    for (int k = threadIdx.x; k < NBUCK; k += 256) {
        int c = cnt[k];
        runStart[k] = c ? atomicAdd(&cursor[k], c) : 0;
    }
    __syncthreads();
    #pragma unroll
    for (int it = 0; it < CHUNK / 256; ++it) {
        int e = base + it * 256 + threadIdx.x;
        if (e < N_EDGES) {
            int d = col[e];
            int b = d >> 7;
            int r = atomicAdd(&rank[b], 1);
            edges[runStart[b] + r] = ((d & (NPB - 1)) << 17) | row[e];  // src < 2^17
        }
    }
}

// ---------------------------------------------------------------- bucket aggregation
// One block per bucket: 128x64 fp32 accumulators in LDS, coalesced x-row gathers,
// ds_add_f32 accumulation (bank = lane&31 -> 2-way, free), coalesced agg write.
__global__ __launch_bounds__(256) void agg_kernel(const float* __restrict__ x,
                                                  const int* __restrict__ edges,
                                                  const int* __restrict__ base_,
                                                  const int* __restrict__ totals,
                                                  const float* __restrict__ adj_norm,
                                                  float* __restrict__ agg) {
    __shared__ float acc[NPB * D];   // 32 KB
    int tid = threadIdx.x;
    #pragma unroll
    for (int i = 0; i < (NPB * D) / 256; ++i) acc[i * 256 + tid] = 0.f;
    __syncthreads();

    int b = blockIdx.x;
    int s = base_[b];
    int end = s + totals[b];
    int lane = tid & 63, wave = tid >> 6;

    int i = s + wave;
    for (; i + 4 < end; i += 8) {          // unroll 2 over 4-wave stride
        int p0 = edges[i], p1 = edges[i + 4];
        float v0 = x[(size_t)(p0 & 0x1FFFF) * D + lane];
        float v1 = x[(size_t)(p1 & 0x1FFFF) * D + lane];
        atomicAdd(&acc[(p0 >> 17) * D + lane], v0);
        atomicAdd(&acc[(p1 >> 17) * D + lane], v1);
    }
    for (; i < end; i += 4) {
        int p = edges[i];
        atomicAdd(&acc[(p >> 17) * D + lane], x[(size_t)(p & 0x1FFFF) * D + lane]);
    }
    __syncthreads();

    int nb0 = b * NPB;
    #pragma unroll
    for (int f = 0; f < (NPB * D) / (256 * 4); ++f) {   // 8 float4 per thread
        int idx = f * 256 + tid;
        int nl = idx >> 4;
        int gn = nb0 + nl;
        if (gn < N_NODES) {
            int dq = (idx & 15) << 2;
            float inv = 1.0f / adj_norm[gn];
            float4 v = *reinterpret_cast<const float4*>(&acc[nl * D + dq]);
            v.x *= inv; v.y *= inv; v.z *= inv; v.w *= inv;
            *reinterpret_cast<float4*>(&agg[(size_t)gn * D + dq]) = v;
        }
    }
}

// ---------------------------------------------------------------- fused dual GEMM + bias + relu
#define STRIDE 68

__global__ __launch_bounds__(256) void fused_out_kernel(
    const float* __restrict__ x, const float* __restrict__ agg,
    const float* __restrict__ root_W, const float* __restrict__ root_b,
    const float* __restrict__ rel_W, float* __restrict__ out)
{
    __shared__ float in_sh[64 * STRIDE];
    __shared__ float w_sh[64 * STRIDE];

    const int tid = threadIdx.x;
    const int n0 = blockIdx.x * 64;
    const int jq = tid & 15;
    const int nq = tid >> 4;

    float acc[4][4] = {};

    for (int phase = 0; phase < 2; ++phase) {
        const float* __restrict__ W  = phase ? root_W : rel_W;
        const float* __restrict__ In = phase ? x : agg;

        if (phase) __syncthreads();

        #pragma unroll
        for (int r = 0; r < 4; ++r) {
            int f = r * 256 + tid;
            int j = f >> 4;
            int dq = (f & 15) << 2;
            float4 wv = *reinterpret_cast<const float4*>(W + j * 64 + dq);
            *reinterpret_cast<float4*>(&w_sh[j * STRIDE + dq]) = wv;
        }
        #pragma unroll
        for (int r = 0; r < 4; ++r) {
            int f = r * 256 + tid;
            int n = f >> 4;
            int dq = (f & 15) << 2;
            int gn = n0 + n;
            float4 v = make_float4(0.f, 0.f, 0.f, 0.f);
            if (gn < N_NODES)
                v = *reinterpret_cast<const float4*>(In + (size_t)gn * D + dq);
            *reinterpret_cast<float4*>(&in_sh[n * STRIDE + dq]) = v;
        }
        __syncthreads();

        for (int d = 0; d < 64; d += 4) {
            float4 a[4], w[4];
            #pragma unroll
            for (int i = 0; i < 4; ++i)
                a[i] = *reinterpret_cast<const float4*>(&in_sh[(nq + 16 * i) * STRIDE + d]);
            #pragma unroll
            for (int k = 0; k < 4; ++k)
                w[k] = *reinterpret_cast<const float4*>(&w_sh[(jq + 16 * k) * STRIDE + d]);
            #pragma unroll
            for (int i = 0; i < 4; ++i)
                #pragma unroll
                for (int k = 0; k < 4; ++k)
                    acc[i][k] += a[i].x * w[k].x + a[i].y * w[k].y
                               + a[i].z * w[k].z + a[i].w * w[k].w;
        }
    }

    #pragma unroll
    for (int i = 0; i < 4; ++i) {
        int gn = n0 + nq + 16 * i;
        if (gn >= N_NODES) continue;
        #pragma unroll
        for (int k = 0; k < 4; ++k) {
            int j = jq + 16 * k;
            float v = acc[i][k] + root_b[j];
            out[(size_t)gn * D + j] = fmaxf(v, 0.0f);
        }
    }
}

// ---------------------------------------------------------------- launch
extern "C" void kernel_launch(void* const* d_in, const int* in_sizes, int n_in,
                              void* d_out, int out_size, void* d_ws, size_t ws_size,
                              hipStream_t stream)
{
    const float* x        = (const float*)d_in[0];
    const int*   row      = (const int*)d_in[1];
    const int*   col      = (const int*)d_in[2];
    const float* adj_norm = (const float*)d_in[4];
    const float* root_W   = (const float*)d_in[5];
    const float* root_b   = (const float*)d_in[6];
    const float* rel_W    = (const float*)d_in[7];
    float* out = (float*)d_out;

    char* ws = (char*)d_ws;
    float* agg      = (float*)ws;   ws += (size_t)N_NODES * D * 4;   // 25.6 MB
    int* bucketTot  = (int*)ws;     ws += (size_t)NBUCK * 4;
    int* bucketBase = (int*)ws;     ws += (size_t)NBUCK * 4;
    int* bucketCur  = (int*)ws;     ws += (size_t)NBUCK * 4;
    int* edges      = (int*)ws;                                      // 6.4 MB

    zero_totals<<<1, 1024, 0, stream>>>(bucketTot);
    hist_kernel<<<NCHUNK, 256, 0, stream>>>(col, bucketTot);
    scan_kernel<<<1, 1024, 0, stream>>>(bucketTot, bucketBase, bucketCur);
    partition_kernel<<<NCHUNK, 256, 0, stream>>>(row, col, bucketCur, edges);
    agg_kernel<<<NBUCK, 256, 0, stream>>>(x, edges, bucketBase, bucketTot, adj_norm, agg);
    fused_out_kernel<<<(N_NODES + 63) / 64, 256, 0, stream>>>(
        x, agg, root_W, root_b, rel_W, out);
}

// Round 4
// 252.343 us; speedup vs baseline: 3.3443x; 3.3443x over previous
//
#include <hip/hip_runtime.h>

#define N_NODES 100000
#define N_EDGES 1600000
#define D 64
#define NPB 128                                   // nodes per bucket
#define NBUCK ((N_NODES + NPB - 1) / NPB)         // 782
#define CHUNK 8192                                // edges per partition block
#define NCHUNK ((N_EDGES + CHUNK - 1) / CHUNK)    // 196

// ---------------------------------------------------------------- zero bucket totals
__global__ __launch_bounds__(1024) void zero_totals(int* __restrict__ p) {
    int t = threadIdx.x;
    if (t < NBUCK) p[t] = 0;
}

// ---------------------------------------------------------------- bucket histogram (LDS-staged)
__global__ __launch_bounds__(256) void hist_kernel(const int* __restrict__ col,
                                                   int* __restrict__ bucketTotals) {
    __shared__ int h[NBUCK];
    for (int k = threadIdx.x; k < NBUCK; k += 256) h[k] = 0;
    __syncthreads();
    int base = blockIdx.x * CHUNK;
    #pragma unroll
    for (int it = 0; it < CHUNK / 256; ++it) {
        int e = base + it * 256 + threadIdx.x;
        if (e < N_EDGES) atomicAdd(&h[col[e] >> 7], 1);
    }
    __syncthreads();
    for (int k = threadIdx.x; k < NBUCK; k += 256)
        if (h[k]) atomicAdd(&bucketTotals[k], h[k]);
}

// ---------------------------------------------------------------- exclusive scan of 782 totals (1 block)
__global__ __launch_bounds__(1024) void scan_kernel(const int* __restrict__ totals,
                                                    int* __restrict__ base_,
                                                    int* __restrict__ cursor) {
    int tid = threadIdx.x;
    int v = (tid < NBUCK) ? totals[tid] : 0;
    int lane = tid & 63, wave = tid >> 6;
    int s = v;
    #pragma unroll
    for (int o = 1; o < 64; o <<= 1) {
        int t = __shfl_up(s, o, 64);
        if (lane >= o) s += t;
    }
    __shared__ int ws[16];
    if (lane == 63) ws[wave] = s;
    __syncthreads();
    if (wave == 0 && lane < 16) {
        int w = ws[lane];
        #pragma unroll
        for (int o = 1; o < 16; o <<= 1) {
            int t = __shfl_up(w, o, 64);
            if (lane >= o) w += t;
        }
        ws[lane] = w;
    }
    __syncthreads();
    int excl = s - v + (wave ? ws[wave - 1] : 0);
    if (tid < NBUCK) { base_[tid] = excl; cursor[tid] = excl; }
}

// ---------------------------------------------------------------- partition into bucketed runs
// Block reserves one contiguous run per bucket -> block-private scattered writes.
__global__ __launch_bounds__(256) void partition_kernel(const int* __restrict__ row,
                                                        const int* __restrict__ col,
                                                        int* __restrict__ cursor,
                                                        int* __restrict__ edges) {
    __shared__ int cnt[NBUCK];
    __shared__ int runStart[NBUCK];
    __shared__ int rank[NBUCK];
    for (int k = threadIdx.x; k < NBUCK; k += 256) { cnt[k] = 0; rank[k] = 0; }
    __syncthreads();
    int base = blockIdx.x * CHUNK;
    #pragma unroll
    for (int it = 0; it < CHUNK / 256; ++it) {
        int e = base + it * 256 + threadIdx.x;
        if (e < N_EDGES) atomicAdd(&cnt[col[e] >> 7], 1);
    }
    __syncthreads();
    for (int k = threadIdx.x; k < NBUCK; k += 256) {
        int c = cnt[k];
        runStart[k] = c ? atomicAdd(&cursor[k], c) : 0;
    }
    __syncthreads();
    #pragma unroll
    for (int it = 0; it < CHUNK / 256; ++it) {
        int e = base + it * 256 + threadIdx.x;
        if (e < N_EDGES) {
            int d = col[e];
            int b = d >> 7;
            int r = atomicAdd(&rank[b], 1);
            edges[runStart[b] + r] = ((d & (NPB - 1)) << 17) | row[e];  // src < 2^17
        }
    }
}

// ---------------------------------------------------------------- per-bucket counting sort -> per-node CSR
// One block per bucket. Bucket's CSR segment == its partition segment, so all
// scattered writes stay in this block's own contiguous ~8KB region.
__global__ __launch_bounds__(256) void sort_kernel(const int* __restrict__ edges,
                                                   const int* __restrict__ base_,
                                                   const int* __restrict__ totals,
                                                   int* __restrict__ edge_src,
                                                   int* __restrict__ off,
                                                   int* __restrict__ deg) {
    __shared__ int cnt[NPB];
    __shared__ int offL[NPB];
    __shared__ int cur[NPB];
    int tid = threadIdx.x;
    int b = blockIdx.x;
    int base = base_[b];
    int tot = totals[b];

    if (tid < NPB) cnt[tid] = 0;
    __syncthreads();
    for (int i = base + tid; i < base + tot; i += 256)
        atomicAdd(&cnt[edges[i] >> 17], 1);
    __syncthreads();

    if (tid < 64) {                          // wave 0: scan 128 bins, 2 per lane
        int v0 = cnt[2 * tid], v1 = cnt[2 * tid + 1];
        int s = v0 + v1;
        #pragma unroll
        for (int o = 1; o < 64; o <<= 1) {
            int t = __shfl_up(s, o, 64);
            if (tid >= o) s += t;
        }
        offL[2 * tid]     = s - v1 - v0;     // exclusive
        offL[2 * tid + 1] = s - v1;
        cur[2 * tid]      = s - v1 - v0;
        cur[2 * tid + 1]  = s - v1;
    }
    __syncthreads();

    for (int i = base + tid; i < base + tot; i += 256) {
        int p = edges[i];
        int l = p >> 17;
        int r = atomicAdd(&cur[l], 1);
        edge_src[base + r] = p & 0x1FFFF;
    }

    if (tid < NPB) {
        int gn = b * NPB + tid;
        if (gn < N_NODES) {
            off[gn] = base + offL[tid];
            deg[gn] = cnt[tid];
        }
    }
}

// ---------------------------------------------------------------- gather aggregation: one wave per node
__global__ __launch_bounds__(256) void agg_kernel(const float* __restrict__ x,
                                                  const int* __restrict__ edge_src,
                                                  const int* __restrict__ off,
                                                  const int* __restrict__ deg,
                                                  const float* __restrict__ adj_norm,
                                                  float* __restrict__ agg) {
    int w = (blockIdx.x * 256 + threadIdx.x) >> 6;    // node id
    int lane = threadIdx.x & 63;
    if (w >= N_NODES) return;
    int s = off[w];
    int end = s + deg[w];
    float acc = 0.f;
    int i = s;
    for (; i + 4 <= end; i += 4) {
        int s0 = edge_src[i + 0], s1 = edge_src[i + 1];
        int s2 = edge_src[i + 2], s3 = edge_src[i + 3];
        float v0 = x[(size_t)s0 * D + lane];
        float v1 = x[(size_t)s1 * D + lane];
        float v2 = x[(size_t)s2 * D + lane];
        float v3 = x[(size_t)s3 * D + lane];
        acc += v0 + v1 + v2 + v3;
    }
    for (; i < end; ++i) acc += x[(size_t)edge_src[i] * D + lane];
    agg[(size_t)w * D + lane] = acc / adj_norm[w];
}

// ---------------------------------------------------------------- fused dual GEMM + bias + relu
#define STRIDE 68

__global__ __launch_bounds__(256) void fused_out_kernel(
    const float* __restrict__ x, const float* __restrict__ agg,
    const float* __restrict__ root_W, const float* __restrict__ root_b,
    const float* __restrict__ rel_W, float* __restrict__ out)
{
    __shared__ float in_sh[64 * STRIDE];
    __shared__ float w_sh[64 * STRIDE];

    const int tid = threadIdx.x;
    const int n0 = blockIdx.x * 64;
    const int jq = tid & 15;
    const int nq = tid >> 4;

    float acc[4][4] = {};

    for (int phase = 0; phase < 2; ++phase) {
        const float* __restrict__ W  = phase ? root_W : rel_W;
        const float* __restrict__ In = phase ? x : agg;

        if (phase) __syncthreads();

        #pragma unroll
        for (int r = 0; r < 4; ++r) {
            int f = r * 256 + tid;
            int j = f >> 4;
            int dq = (f & 15) << 2;
            float4 wv = *reinterpret_cast<const float4*>(W + j * 64 + dq);
            *reinterpret_cast<float4*>(&w_sh[j * STRIDE + dq]) = wv;
        }
        #pragma unroll
        for (int r = 0; r < 4; ++r) {
            int f = r * 256 + tid;
            int n = f >> 4;
            int dq = (f & 15) << 2;
            int gn = n0 + n;
            float4 v = make_float4(0.f, 0.f, 0.f, 0.f);
            if (gn < N_NODES)
                v = *reinterpret_cast<const float4*>(In + (size_t)gn * D + dq);
            *reinterpret_cast<float4*>(&in_sh[n * STRIDE + dq]) = v;
        }
        __syncthreads();

        for (int d = 0; d < 64; d += 4) {
            float4 a[4], w[4];
            #pragma unroll
            for (int i = 0; i < 4; ++i)
                a[i] = *reinterpret_cast<const float4*>(&in_sh[(nq + 16 * i) * STRIDE + d]);
            #pragma unroll
            for (int k = 0; k < 4; ++k)
                w[k] = *reinterpret_cast<const float4*>(&w_sh[(jq + 16 * k) * STRIDE + d]);
            #pragma unroll
            for (int i = 0; i < 4; ++i)
                #pragma unroll
                for (int k = 0; k < 4; ++k)
                    acc[i][k] += a[i].x * w[k].x + a[i].y * w[k].y
                               + a[i].z * w[k].z + a[i].w * w[k].w;
        }
    }

    #pragma unroll
    for (int i = 0; i < 4; ++i) {
        int gn = n0 + nq + 16 * i;
        if (gn >= N_NODES) continue;
        #pragma unroll
        for (int k = 0; k < 4; ++k) {
            int j = jq + 16 * k;
            float v = acc[i][k] + root_b[j];
            out[(size_t)gn * D + j] = fmaxf(v, 0.0f);
        }
    }
}

// ---------------------------------------------------------------- launch
extern "C" void kernel_launch(void* const* d_in, const int* in_sizes, int n_in,
                              void* d_out, int out_size, void* d_ws, size_t ws_size,
                              hipStream_t stream)
{
    const float* x        = (const float*)d_in[0];
    const int*   row      = (const int*)d_in[1];
    const int*   col      = (const int*)d_in[2];
    const float* adj_norm = (const float*)d_in[4];
    const float* root_W   = (const float*)d_in[5];
    const float* root_b   = (const float*)d_in[6];
    const float* rel_W    = (const float*)d_in[7];
    float* out = (float*)d_out;

    char* ws = (char*)d_ws;
    float* agg      = (float*)ws;   ws += (size_t)N_NODES * D * 4;   // 25.6 MB
    int* bucketTot  = (int*)ws;     ws += (size_t)NBUCK * 4;
    int* bucketBase = (int*)ws;     ws += (size_t)NBUCK * 4;
    int* bucketCur  = (int*)ws;     ws += (size_t)NBUCK * 4;
    int* off        = (int*)ws;     ws += (size_t)N_NODES * 4;
    int* deg        = (int*)ws;     ws += (size_t)N_NODES * 4;
    int* edges      = (int*)ws;     ws += (size_t)N_EDGES * 4;       // 6.4 MB
    int* edge_src   = (int*)ws;                                      // 6.4 MB

    zero_totals<<<1, 1024, 0, stream>>>(bucketTot);
    hist_kernel<<<NCHUNK, 256, 0, stream>>>(col, bucketTot);
    scan_kernel<<<1, 1024, 0, stream>>>(bucketTot, bucketBase, bucketCur);
    partition_kernel<<<NCHUNK, 256, 0, stream>>>(row, col, bucketCur, edges);
    sort_kernel<<<NBUCK, 256, 0, stream>>>(edges, bucketBase, bucketTot, edge_src, off, deg);

    const int aggThreads = N_NODES * 64;
    agg_kernel<<<(aggThreads + 255) / 256, 256, 0, stream>>>(x, edge_src, off, deg, adj_norm, agg);

    fused_out_kernel<<<(N_NODES + 63) / 64, 256, 0, stream>>>(
        x, agg, root_W, root_b, rel_W, out);
}